// Round 8
// baseline (826.578 us; speedup 1.0000x reference)
//
#include <hip/hip_runtime.h>
#include <hip/hip_bf16.h>

// ---------------- small helpers ----------------
__device__ __forceinline__ float4 f4_fma(float4 a, float s, float4 acc) {
    acc.x = fmaf(a.x, s, acc.x); acc.y = fmaf(a.y, s, acc.y);
    acc.z = fmaf(a.z, s, acc.z); acc.w = fmaf(a.w, s, acc.w);
    return acc;
}
__device__ __forceinline__ float4 f4_add(float4 a, float4 b) {
    return make_float4(a.x + b.x, a.y + b.y, a.z + b.z, a.w + b.w);
}

// ---------------- degree count ----------------
__global__ __launch_bounds__(256) void cnt_count_kernel(const int* __restrict__ dst, int* cnt, int E) {
    int i = blockIdx.x * blockDim.x + threadIdx.x;
    if (i < E) atomicAdd(&cnt[dst[i]], 1);
}

// ---------------- exclusive scan (N ~ 100k) ----------------
#define SCAN_CHUNK 4096  // 256 threads * 16

__global__ __launch_bounds__(256) void scan_reduce_kernel(const int* __restrict__ cnt, int* bsum, int N) {
    __shared__ int sdata[256];
    int base = blockIdx.x * SCAN_CHUNK;
    int s = 0;
    for (int k = 0; k < 16; ++k) {
        int i = base + k * 256 + threadIdx.x;
        if (i < N) s += cnt[i];
    }
    sdata[threadIdx.x] = s;
    __syncthreads();
    for (int off = 128; off > 0; off >>= 1) {
        if (threadIdx.x < off) sdata[threadIdx.x] += sdata[threadIdx.x + off];
        __syncthreads();
    }
    if (threadIdx.x == 0) bsum[blockIdx.x] = sdata[0];
}

__global__ void scan_bsum_kernel(int* bsum, int B, int* rowptr_end, int E) {
    if (threadIdx.x == 0 && blockIdx.x == 0) {
        int run = 0;
        for (int i = 0; i < B; ++i) { int v = bsum[i]; bsum[i] = run; run += v; }
        *rowptr_end = E;  // rowptr[N] = E
    }
}

// also emits dinv (rsqrt(deg)) and cursor (= rowptr copy)
__global__ __launch_bounds__(256) void scan_write_kernel(const int* __restrict__ cnt,
                                                         const int* __restrict__ bsum,
                                                         int* rowptr, int* cursor,
                                                         float* dinv, int N) {
    __shared__ int sdata[256];
    int base = blockIdx.x * SCAN_CHUNK;
    int tbase = base + threadIdx.x * 16;
    int loc[16];
    int s = 0;
    for (int k = 0; k < 16; ++k) {
        int i = tbase + k;
        int v = (i < N) ? cnt[i] : 0;
        loc[k] = s; s += v;
    }
    sdata[threadIdx.x] = s;
    __syncthreads();
    for (int off = 1; off < 256; off <<= 1) {
        int v = sdata[threadIdx.x];
        int add = (threadIdx.x >= off) ? sdata[threadIdx.x - off] : 0;
        __syncthreads();
        sdata[threadIdx.x] = v + add;
        __syncthreads();
    }
    int texcl = (threadIdx.x == 0) ? 0 : sdata[threadIdx.x - 1];
    int boff = bsum[blockIdx.x];
    for (int k = 0; k < 16; ++k) {
        int i = tbase + k;
        if (i < N) {
            int rp = boff + texcl + loc[k];
            rowptr[i] = rp;
            cursor[i] = rp;
            dinv[i] = rsqrtf((float)(cnt[i] + 1));
        }
    }
}

// ---------------- heterogeneous: csr_fill (blocks [0,gFill)) || gemm1 (blocks [gFill,gFill+G1_GRID)) ----------------
// csr_fill is latency/transaction-bound, gemm1 is VALU-bound; gemm1 (~70us) hides under fill (~130us).
// gemm1 tile kept at 16KB LDS so fill blocks are not LDS-capped (8 blocks/CU).
#define G1_GRID 512
#define G1_TILE 32

__global__ __launch_bounds__(256) void fill_and_gemm1(const int* __restrict__ src,
                                                      const int* __restrict__ dst,
                                                      int* cursor, int* __restrict__ col,
                                                      int E, int gFill,
                                                      const float* __restrict__ x,
                                                      const float* __restrict__ W1,
                                                      const float* __restrict__ dinv,
                                                      float* __restrict__ t,
                                                      int N, int n1tiles) {
    __shared__ float hl[G1_TILE * 128];  // 16 KB
    int bid = blockIdx.x;
    if (bid < gFill) {
        int e = bid * 256 + threadIdx.x;
        if (e < E) {
            int s = src[e], d = dst[e];
            int pos = atomicAdd(&cursor[d], 1);
            col[pos] = s;
        }
        return;
    }
    // gemm1: t[row][128] = (x[row][128] @ W1) * dinv[row]
    const int jf4 = threadIdx.x & 31;
    const int rg  = threadIdx.x >> 5;  // 0..7 -> rows rg*4..rg*4+3
    const float* wptr = W1 + jf4 * 4;
    for (long long tile = bid - gFill; tile < n1tiles; tile += G1_GRID) {
        long long row0 = tile * (long long)G1_TILE;
        for (int i = threadIdx.x; i < G1_TILE * 32; i += 256) {
            int rl = i >> 5, k4 = i & 31;
            long long row = row0 + rl;
            float4 v = (row < N) ? ((const float4*)x)[row * 32 + k4]
                                 : make_float4(0.f, 0.f, 0.f, 0.f);
            *(float4*)&hl[rl * 128 + k4 * 4] = v;
        }
        __syncthreads();
        float4 acc[4];
        #pragma unroll
        for (int rr = 0; rr < 4; ++rr) acc[rr] = make_float4(0.f, 0.f, 0.f, 0.f);
        const float* hb = &hl[rg * 4 * 128];
        #pragma unroll 4
        for (int k = 0; k < 128; k += 4) {
            float4 w0 = *(const float4*)&wptr[(size_t)(k + 0) * 128];
            float4 w1 = *(const float4*)&wptr[(size_t)(k + 1) * 128];
            float4 w2 = *(const float4*)&wptr[(size_t)(k + 2) * 128];
            float4 w3 = *(const float4*)&wptr[(size_t)(k + 3) * 128];
            #pragma unroll
            for (int rr = 0; rr < 4; ++rr) {
                float4 hv = *(const float4*)&hb[rr * 128 + k];
                acc[rr] = f4_fma(w0, hv.x, acc[rr]);
                acc[rr] = f4_fma(w1, hv.y, acc[rr]);
                acc[rr] = f4_fma(w2, hv.z, acc[rr]);
                acc[rr] = f4_fma(w3, hv.w, acc[rr]);
            }
        }
        #pragma unroll
        for (int rr = 0; rr < 4; ++rr) {
            long long row = row0 + rg * 4 + rr;
            if (row < N) {
                float di = dinv[row];
                float4 r = acc[rr];
                r.x *= di; r.y *= di; r.z *= di; r.w *= di;
                ((float4*)t)[row * 32 + jf4] = r;
            }
        }
        __syncthreads();
    }
}

// ---------------- fused agg(layer k) + gemm(layer k+1), 512 threads ----------------
// Block owns 64 dst rows; 16 groups x 32 lanes; each group aggregates 4 rows into
// its own LDS rows (phase A) and computes the GEMM for exactly those rows (phase B).
// No block barrier: producer wave == consumer wave (wave w = groups 2w,2w+1 = rows
// 8w..8w+7 in both phases). 32KB LDS + 512 thr -> 4 blocks/CU = 32 waves (full).
#define TILE_R 64

__global__ __launch_bounds__(512) void fused_agg_gemm(const float4* __restrict__ t4,
                                                      const int* __restrict__ rowptr,
                                                      const int* __restrict__ col,
                                                      const float* __restrict__ dinv,
                                                      const float* __restrict__ bvec,
                                                      const float* __restrict__ Wa,
                                                      const float* __restrict__ Wb,
                                                      float* __restrict__ tout,
                                                      int N) {
    __shared__ float hl[TILE_R * 128];  // 32 KB

    const int grp = threadIdx.x >> 5;   // 0..15
    const int c   = threadIdx.x & 31;   // float4 col
    const long long row0 = (long long)blockIdx.x * TILE_R;

    // Phase A: each group aggregates its 4 rows into LDS (with relu)
    float4 bb = ((const float4*)bvec)[c];
    #pragma unroll 1
    for (int r = 0; r < 4; ++r) {
        long long v = row0 + grp * 4 + r;
        float4 res;
        if (v < N) {
            int beg = rowptr[v], end = rowptr[v + 1];
            float4 acc0 = t4[(size_t)v * 32 + c];  // self-loop (pre-scaled)
            float4 acc1 = make_float4(0.f, 0.f, 0.f, 0.f);
            float4 acc2 = make_float4(0.f, 0.f, 0.f, 0.f);
            float4 acc3 = make_float4(0.f, 0.f, 0.f, 0.f);
            int e = beg;
            for (; e + 7 < end; e += 8) {
                int s0 = col[e],     s1 = col[e + 1], s2 = col[e + 2], s3 = col[e + 3];
                int s4 = col[e + 4], s5 = col[e + 5], s6 = col[e + 6], s7 = col[e + 7];
                float4 v0 = t4[(size_t)s0 * 32 + c];
                float4 v1 = t4[(size_t)s1 * 32 + c];
                float4 v2 = t4[(size_t)s2 * 32 + c];
                float4 v3 = t4[(size_t)s3 * 32 + c];
                float4 v4 = t4[(size_t)s4 * 32 + c];
                float4 v5 = t4[(size_t)s5 * 32 + c];
                float4 v6 = t4[(size_t)s6 * 32 + c];
                float4 v7 = t4[(size_t)s7 * 32 + c];
                acc0 = f4_add(acc0, v0); acc1 = f4_add(acc1, v1);
                acc2 = f4_add(acc2, v2); acc3 = f4_add(acc3, v3);
                acc0 = f4_add(acc0, v4); acc1 = f4_add(acc1, v5);
                acc2 = f4_add(acc2, v6); acc3 = f4_add(acc3, v7);
            }
            for (; e + 3 < end; e += 4) {
                int s0 = col[e], s1 = col[e + 1], s2 = col[e + 2], s3 = col[e + 3];
                acc0 = f4_add(acc0, t4[(size_t)s0 * 32 + c]);
                acc1 = f4_add(acc1, t4[(size_t)s1 * 32 + c]);
                acc2 = f4_add(acc2, t4[(size_t)s2 * 32 + c]);
                acc3 = f4_add(acc3, t4[(size_t)s3 * 32 + c]);
            }
            for (; e < end; ++e) acc0 = f4_add(acc0, t4[(size_t)col[e] * 32 + c]);
            float di = dinv[v];
            float4 s = f4_add(f4_add(acc0, acc1), f4_add(acc2, acc3));
            res = f4_fma(s, di, bb);
            res.x = fmaxf(res.x, 0.f); res.y = fmaxf(res.y, 0.f);
            res.z = fmaxf(res.z, 0.f); res.w = fmaxf(res.w, 0.f);
        } else {
            res = make_float4(0.f, 0.f, 0.f, 0.f);
        }
        *(float4*)&hl[(grp * 4 + r) * 128 + c * 4] = res;
    }
    // (no __syncthreads: intra-wave LDS RAW only)

    // Phase B: GEMM from LDS (thread: its group's 4 rows x 4 cols)
    const int jf4 = c;
    const float* wptr;
    int wstride;
    if (Wb) { wptr = (jf4 < 16) ? (Wa + jf4 * 4) : (Wb + (jf4 - 16) * 4); wstride = 64; }
    else    { wptr = Wa + jf4 * 4; wstride = 128; }

    float4 acc[4];
    #pragma unroll
    for (int rr = 0; rr < 4; ++rr) acc[rr] = make_float4(0.f, 0.f, 0.f, 0.f);

    const float* hb = &hl[grp * 4 * 128];
    #pragma unroll 4
    for (int k = 0; k < 128; k += 4) {
        float4 w0 = *(const float4*)&wptr[(size_t)(k + 0) * wstride];
        float4 w1 = *(const float4*)&wptr[(size_t)(k + 1) * wstride];
        float4 w2 = *(const float4*)&wptr[(size_t)(k + 2) * wstride];
        float4 w3 = *(const float4*)&wptr[(size_t)(k + 3) * wstride];
        #pragma unroll
        for (int rr = 0; rr < 4; ++rr) {
            float4 hv = *(const float4*)&hb[rr * 128 + k];
            acc[rr] = f4_fma(w0, hv.x, acc[rr]);
            acc[rr] = f4_fma(w1, hv.y, acc[rr]);
            acc[rr] = f4_fma(w2, hv.z, acc[rr]);
            acc[rr] = f4_fma(w3, hv.w, acc[rr]);
        }
    }

    #pragma unroll
    for (int rr = 0; rr < 4; ++rr) {
        long long row = row0 + grp * 4 + rr;
        if (row < N) {
            float di = dinv[row];
            float4 r = acc[rr];
            r.x *= di; r.y *= di; r.z *= di; r.w *= di;
            ((float4*)tout)[row * 32 + jf4] = r;
        }
    }
}

// final layer: cols 0..63 -> mu, 64..127 -> logstd (split output)
__global__ __launch_bounds__(256) void agg_pull_final_kernel(const float4* __restrict__ t4,
                                                             const int* __restrict__ rowptr,
                                                             const int* __restrict__ col,
                                                             const float* __restrict__ dinv,
                                                             const float* __restrict__ bmu,
                                                             const float* __restrict__ bls,
                                                             float4* __restrict__ out4,
                                                             int N) {
    int v = blockIdx.x * 8 + (threadIdx.x >> 5);
    int c = threadIdx.x & 31;
    if (v >= N) return;
    int half = c >> 4, cc = c & 15;
    int beg = rowptr[v], end = rowptr[v + 1];
    float4 acc0 = t4[(size_t)v * 32 + c];
    float4 acc1 = make_float4(0.f, 0.f, 0.f, 0.f);
    float4 acc2 = make_float4(0.f, 0.f, 0.f, 0.f);
    float4 acc3 = make_float4(0.f, 0.f, 0.f, 0.f);
    int e = beg;
    for (; e + 7 < end; e += 8) {
        int s0 = col[e],     s1 = col[e + 1], s2 = col[e + 2], s3 = col[e + 3];
        int s4 = col[e + 4], s5 = col[e + 5], s6 = col[e + 6], s7 = col[e + 7];
        float4 v0 = t4[(size_t)s0 * 32 + c];
        float4 v1 = t4[(size_t)s1 * 32 + c];
        float4 v2 = t4[(size_t)s2 * 32 + c];
        float4 v3 = t4[(size_t)s3 * 32 + c];
        float4 v4 = t4[(size_t)s4 * 32 + c];
        float4 v5 = t4[(size_t)s5 * 32 + c];
        float4 v6 = t4[(size_t)s6 * 32 + c];
        float4 v7 = t4[(size_t)s7 * 32 + c];
        acc0 = f4_add(acc0, v0); acc1 = f4_add(acc1, v1);
        acc2 = f4_add(acc2, v2); acc3 = f4_add(acc3, v3);
        acc0 = f4_add(acc0, v4); acc1 = f4_add(acc1, v5);
        acc2 = f4_add(acc2, v6); acc3 = f4_add(acc3, v7);
    }
    for (; e + 3 < end; e += 4) {
        int s0 = col[e], s1 = col[e + 1], s2 = col[e + 2], s3 = col[e + 3];
        acc0 = f4_add(acc0, t4[(size_t)s0 * 32 + c]);
        acc1 = f4_add(acc1, t4[(size_t)s1 * 32 + c]);
        acc2 = f4_add(acc2, t4[(size_t)s2 * 32 + c]);
        acc3 = f4_add(acc3, t4[(size_t)s3 * 32 + c]);
    }
    for (; e < end; ++e) acc0 = f4_add(acc0, t4[(size_t)col[e] * 32 + c]);
    float di = dinv[v];
    float4 s = f4_add(f4_add(acc0, acc1), f4_add(acc2, acc3));
    float4 bb = half ? ((const float4*)bls)[cc] : ((const float4*)bmu)[cc];
    out4[(size_t)half * N * 16 + (size_t)v * 16 + cc] = f4_fma(s, di, bb);
}

// ---------------- fallback (atomic scatter) kernels ----------------
__global__ __launch_bounds__(256) void deg_init_kernel(float* deg, int N) {
    int i = blockIdx.x * blockDim.x + threadIdx.x;
    if (i < N) deg[i] = 1.0f;
}
__global__ __launch_bounds__(256) void deg_count_kernel(const int* __restrict__ dst, float* deg, int E) {
    int i = blockIdx.x * blockDim.x + threadIdx.x;
    if (i < E) unsafeAtomicAdd(&deg[dst[i]], 1.0f);
}
__global__ __launch_bounds__(256) void deg_rsqrt_kernel(float* deg, int N) {
    int i = blockIdx.x * blockDim.x + threadIdx.x;
    if (i < N) deg[i] = rsqrtf(deg[i]);
}
__global__ __launch_bounds__(256) void gemm128_kernel(const float* __restrict__ h,
                                                      const float* __restrict__ Wa,
                                                      const float* __restrict__ Wb,
                                                      float* __restrict__ t,
                                                      int N, int relu) {
    __shared__ float Wl[128 * 128];
    __shared__ float hl[2][128];
    for (int i = threadIdx.x; i < 128 * 128; i += 256) {
        int k = i >> 7, j = i & 127;
        float w;
        if (Wb) w = (j < 64) ? Wa[k * 64 + j] : Wb[k * 64 + (j - 64)];
        else    w = Wa[i];
        Wl[i] = w;
    }
    __syncthreads();
    int col = threadIdx.x & 127;
    int r   = threadIdx.x >> 7;
    for (long long pair = blockIdx.x; pair * 2 < N; pair += gridDim.x) {
        int row0 = (int)(pair * 2);
        {
            int rr = threadIdx.x >> 7, k = threadIdx.x & 127;
            int row = row0 + rr;
            float v = (row < N) ? h[(size_t)row * 128 + k] : 0.0f;
            if (relu) v = fmaxf(v, 0.0f);
            hl[rr][k] = v;
        }
        __syncthreads();
        float acc = 0.0f;
        #pragma unroll
        for (int k = 0; k < 128; k += 4) {
            float4 hv = *(const float4*)&hl[r][k];
            acc += hv.x * Wl[(k + 0) * 128 + col];
            acc += hv.y * Wl[(k + 1) * 128 + col];
            acc += hv.z * Wl[(k + 2) * 128 + col];
            acc += hv.w * Wl[(k + 3) * 128 + col];
        }
        int row = row0 + r;
        if (row < N) t[(size_t)row * 128 + col] = acc;
        __syncthreads();
    }
}
__global__ __launch_bounds__(256) void init_self_kernel(const float4* __restrict__ t4,
                                                        const float* __restrict__ dinv,
                                                        const float* __restrict__ b,
                                                        float4* __restrict__ out, int N) {
    int idx = blockIdx.x * blockDim.x + threadIdx.x;
    int v = idx >> 5, c = idx & 31;
    if (v >= N) return;
    float di = dinv[v];
    float s = di * di;
    float4 x = t4[(size_t)v * 32 + c];
    float4 bb = ((const float4*)b)[c];
    out[(size_t)v * 32 + c] = make_float4(fmaf(x.x, s, bb.x), fmaf(x.y, s, bb.y),
                                          fmaf(x.z, s, bb.z), fmaf(x.w, s, bb.w));
}
__global__ __launch_bounds__(256) void init_final_kernel(const float4* __restrict__ t4,
                                                         const float* __restrict__ dinv,
                                                         const float* __restrict__ bmu,
                                                         const float* __restrict__ bls,
                                                         float4* __restrict__ out4, int N) {
    int idx = blockIdx.x * blockDim.x + threadIdx.x;
    int v = idx >> 5, c = idx & 31;
    if (v >= N) return;
    int half = c >> 4, cc = c & 15;
    float di = dinv[v];
    float s = di * di;
    float4 x = t4[(size_t)v * 32 + c];
    float4 bb = half ? ((const float4*)bls)[cc] : ((const float4*)bmu)[cc];
    out4[(size_t)half * N * 16 + (size_t)v * 16 + cc] =
        make_float4(fmaf(x.x, s, bb.x), fmaf(x.y, s, bb.y),
                    fmaf(x.z, s, bb.z), fmaf(x.w, s, bb.w));
}
__global__ __launch_bounds__(256) void agg_edge_kernel(const float4* __restrict__ t4,
                                                       const int* __restrict__ src,
                                                       const int* __restrict__ dst,
                                                       const float* __restrict__ dinv,
                                                       float* __restrict__ out, int E) {
    int idx = blockIdx.x * blockDim.x + threadIdx.x;
    int e = idx >> 5, c = idx & 31;
    if (e >= E) return;
    int s = src[e], d = dst[e];
    float w = dinv[s] * dinv[d];
    float4 v = t4[(size_t)s * 32 + c];
    float* o = out + (size_t)d * 128 + c * 4;
    unsafeAtomicAdd(o + 0, v.x * w);
    unsafeAtomicAdd(o + 1, v.y * w);
    unsafeAtomicAdd(o + 2, v.z * w);
    unsafeAtomicAdd(o + 3, v.w * w);
}
__global__ __launch_bounds__(256) void agg_edge_final_kernel(const float4* __restrict__ t4,
                                                             const int* __restrict__ src,
                                                             const int* __restrict__ dst,
                                                             const float* __restrict__ dinv,
                                                             float* __restrict__ out, int N, int E) {
    int idx = blockIdx.x * blockDim.x + threadIdx.x;
    int e = idx >> 5, c = idx & 31;
    if (e >= E) return;
    int s = src[e], d = dst[e];
    int half = c >> 4, cc = c & 15;
    float w = dinv[s] * dinv[d];
    float4 v = t4[(size_t)s * 32 + c];
    float* o = out + (size_t)half * N * 64 + (size_t)d * 64 + cc * 4;
    unsafeAtomicAdd(o + 0, v.x * w);
    unsafeAtomicAdd(o + 1, v.y * w);
    unsafeAtomicAdd(o + 2, v.z * w);
    unsafeAtomicAdd(o + 3, v.w * w);
}

// ---------------- launch ----------------
extern "C" void kernel_launch(void* const* d_in, const int* in_sizes, int n_in,
                              void* d_out, int out_size, void* d_ws, size_t ws_size,
                              hipStream_t stream) {
    const float* x   = (const float*)d_in[0];
    const int*   ei  = (const int*)d_in[1];
    const float* W1  = (const float*)d_in[2];
    const float* b1  = (const float*)d_in[3];
    const float* W2  = (const float*)d_in[4];
    const float* b2  = (const float*)d_in[5];
    const float* Wmu = (const float*)d_in[6];
    const float* bmu = (const float*)d_in[7];
    const float* Wls = (const float*)d_in[8];
    const float* bls = (const float*)d_in[9];

    const int N = in_sizes[0] / 128;
    const int E = in_sizes[1] / 2;
    const int* src = ei;
    const int* dst = ei + E;

    float* out = (float*)d_out;

    auto align256 = [](size_t o) { return (o + 255) & ~(size_t)255; };
    const int B1 = (N + SCAN_CHUNK - 1) / SCAN_CHUNK;

    size_t off = 0;
    size_t o_dinv   = off; off = align256(off + (size_t)N * 4);
    size_t o_t      = off; off = align256(off + (size_t)N * 128 * 4);
    size_t o_t2     = off; off = align256(off + (size_t)N * 128 * 4);
    size_t o_rowptr = off; off = align256(off + (size_t)(N + 1) * 4);
    size_t o_cursor = off; off = align256(off + (size_t)N * 4);       // also cnt
    size_t o_bsum   = off; off = align256(off + (size_t)B1 * 4);
    size_t o_col    = off; off = align256(off + (size_t)E * 4);
    size_t need = off;

    float* dinv = (float*)((char*)d_ws + o_dinv);
    float* t    = (float*)((char*)d_ws + o_t);
    float* t2   = (float*)((char*)d_ws + o_t2);

    const int TB = 256;
    int gN = (N + TB - 1) / TB;
    int gE = (E + TB - 1) / TB;
    int ntiles  = (N + TILE_R - 1) / TILE_R;
    int n1tiles = (N + G1_TILE - 1) / G1_TILE;

    if (ws_size >= need) {
        int* rowptr = (int*)((char*)d_ws + o_rowptr);
        int* cursor = (int*)((char*)d_ws + o_cursor);
        int* bsum   = (int*)((char*)d_ws + o_bsum);
        int* col    = (int*)((char*)d_ws + o_col);

        // CSR build prologue
        hipMemsetAsync(cursor, 0, (size_t)N * 4, stream);
        cnt_count_kernel<<<gE, TB, 0, stream>>>(dst, cursor, E);
        scan_reduce_kernel<<<B1, TB, 0, stream>>>(cursor, bsum, N);
        scan_bsum_kernel<<<1, 64, 0, stream>>>(bsum, B1, rowptr + N, E);
        scan_write_kernel<<<B1, TB, 0, stream>>>(cursor, bsum, rowptr, cursor, dinv, N);

        // csr_fill || layer-1 gemm (independent; dinv ready)
        fill_and_gemm1<<<gE + G1_GRID, TB, 0, stream>>>(src, dst, cursor, col, E, gE,
                                                        x, W1, dinv, t, N, n1tiles);

        // layer 2 fused: h1 = relu(agg(t)+b1); t2 = (h1 @ W2) * dinv
        fused_agg_gemm<<<ntiles, 512, 0, stream>>>((const float4*)t, rowptr, col, dinv, b1, W2, nullptr, t2, N);
        // layer 3 fused: h2 = relu(agg(t2)+b2); t = (h2 @ [Wmu|Wls]) * dinv
        fused_agg_gemm<<<ntiles, 512, 0, stream>>>((const float4*)t2, rowptr, col, dinv, b2, Wmu, Wls, t, N);
        // layer 4: final aggregation -> (mu, logstd)
        agg_pull_final_kernel<<<(N + 7) / 8, TB, 0, stream>>>((const float4*)t, rowptr, col, dinv, bmu, bls, (float4*)out, N);
    } else {
        // fallback: atomic scatter path
        int gN32  = (N * 32 + TB - 1) / TB;
        int gE32h = (int)(((long long)E * 32 + TB - 1) / TB);
        deg_init_kernel<<<gN, TB, 0, stream>>>(dinv, N);
        deg_count_kernel<<<gE, TB, 0, stream>>>(dst, dinv, E);
        deg_rsqrt_kernel<<<gN, TB, 0, stream>>>(dinv, N);

        gemm128_kernel<<<2048, TB, 0, stream>>>(x, W1, nullptr, t, N, 0);
        init_self_kernel<<<gN32, TB, 0, stream>>>((const float4*)t, dinv, b1, (float4*)out, N);
        agg_edge_kernel<<<gE32h, TB, 0, stream>>>((const float4*)t, src, dst, dinv, out, E);

        gemm128_kernel<<<2048, TB, 0, stream>>>(out, W2, nullptr, t, N, 1);
        init_self_kernel<<<gN32, TB, 0, stream>>>((const float4*)t, dinv, b2, (float4*)out, N);
        agg_edge_kernel<<<gE32h, TB, 0, stream>>>((const float4*)t, src, dst, dinv, out, E);

        gemm128_kernel<<<2048, TB, 0, stream>>>(out, Wmu, Wls, t, N, 1);
        init_final_kernel<<<gN32, TB, 0, stream>>>((const float4*)t, dinv, bmu, bls, (float4*)out, N);
        agg_edge_final_kernel<<<gE32h, TB, 0, stream>>>((const float4*)t, src, dst, dinv, out, N, E);
    }
}

// Round 9
// 753.801 us; speedup vs baseline: 1.0965x; 1.0965x over previous
//
#include <hip/hip_runtime.h>
#include <hip/hip_bf16.h>

// ---------------- small helpers ----------------
__device__ __forceinline__ float4 f4_fma(float4 a, float s, float4 acc) {
    acc.x = fmaf(a.x, s, acc.x); acc.y = fmaf(a.y, s, acc.y);
    acc.z = fmaf(a.z, s, acc.z); acc.w = fmaf(a.w, s, acc.w);
    return acc;
}
__device__ __forceinline__ float4 f4_add(float4 a, float4 b) {
    return make_float4(a.x + b.x, a.y + b.y, a.z + b.z, a.w + b.w);
}

typedef const __attribute__((address_space(1))) unsigned int* gas_u32;
typedef __attribute__((address_space(3))) unsigned int* las_u32;

__device__ __forceinline__ void gl_lds16(const float* g, float* l) {
    __builtin_amdgcn_global_load_lds((gas_u32)(const void*)g, (las_u32)(void*)l, 16, 0, 0);
}

// ---------------- degree count (4 edges/thread: 4 independent atomics in flight) ----------------
__global__ __launch_bounds__(256) void cnt_count4_kernel(const int4* __restrict__ dst4, int* cnt, int E4) {
    int i = blockIdx.x * blockDim.x + threadIdx.x;
    if (i < E4) {
        int4 d = dst4[i];
        atomicAdd(&cnt[d.x], 1);
        atomicAdd(&cnt[d.y], 1);
        atomicAdd(&cnt[d.z], 1);
        atomicAdd(&cnt[d.w], 1);
    }
}
__global__ __launch_bounds__(256) void cnt_count_kernel(const int* __restrict__ dst, int* cnt, int E) {
    int i = blockIdx.x * blockDim.x + threadIdx.x;
    if (i < E) atomicAdd(&cnt[dst[i]], 1);
}

// ---------------- exclusive scan (N ~ 100k) ----------------
#define SCAN_CHUNK 4096  // 256 threads * 16

__global__ __launch_bounds__(256) void scan_reduce_kernel(const int* __restrict__ cnt, int* bsum, int N) {
    __shared__ int sdata[256];
    int base = blockIdx.x * SCAN_CHUNK;
    int s = 0;
    for (int k = 0; k < 16; ++k) {
        int i = base + k * 256 + threadIdx.x;
        if (i < N) s += cnt[i];
    }
    sdata[threadIdx.x] = s;
    __syncthreads();
    for (int off = 128; off > 0; off >>= 1) {
        if (threadIdx.x < off) sdata[threadIdx.x] += sdata[threadIdx.x + off];
        __syncthreads();
    }
    if (threadIdx.x == 0) bsum[blockIdx.x] = sdata[0];
}

__global__ void scan_bsum_kernel(int* bsum, int B, int* rowptr_end, int E) {
    if (threadIdx.x == 0 && blockIdx.x == 0) {
        int run = 0;
        for (int i = 0; i < B; ++i) { int v = bsum[i]; bsum[i] = run; run += v; }
        *rowptr_end = E;  // rowptr[N] = E
    }
}

// also emits dinv (rsqrt(deg)) and cursor (= rowptr copy)
__global__ __launch_bounds__(256) void scan_write_kernel(const int* __restrict__ cnt,
                                                         const int* __restrict__ bsum,
                                                         int* rowptr, int* cursor,
                                                         float* dinv, int N) {
    __shared__ int sdata[256];
    int base = blockIdx.x * SCAN_CHUNK;
    int tbase = base + threadIdx.x * 16;
    int loc[16];
    int s = 0;
    for (int k = 0; k < 16; ++k) {
        int i = tbase + k;
        int v = (i < N) ? cnt[i] : 0;
        loc[k] = s; s += v;
    }
    sdata[threadIdx.x] = s;
    __syncthreads();
    for (int off = 1; off < 256; off <<= 1) {
        int v = sdata[threadIdx.x];
        int add = (threadIdx.x >= off) ? sdata[threadIdx.x - off] : 0;
        __syncthreads();
        sdata[threadIdx.x] = v + add;
        __syncthreads();
    }
    int texcl = (threadIdx.x == 0) ? 0 : sdata[threadIdx.x - 1];
    int boff = bsum[blockIdx.x];
    for (int k = 0; k < 16; ++k) {
        int i = tbase + k;
        if (i < N) {
            int rp = boff + texcl + loc[k];
            rowptr[i] = rp;
            cursor[i] = rp;
            dinv[i] = rsqrtf((float)(cnt[i] + 1));
        }
    }
}

// ---------------- csr fill (4 edges/thread: independent atomic+store chains overlap) ----------------
__global__ __launch_bounds__(256) void csr_fill4_kernel(const int4* __restrict__ src4,
                                                        const int4* __restrict__ dst4,
                                                        int* cursor, int* __restrict__ col,
                                                        int E4) {
    int i = blockIdx.x * blockDim.x + threadIdx.x;
    if (i >= E4) return;
    int4 s = src4[i];
    int4 d = dst4[i];
    int p0 = atomicAdd(&cursor[d.x], 1);
    int p1 = atomicAdd(&cursor[d.y], 1);
    int p2 = atomicAdd(&cursor[d.z], 1);
    int p3 = atomicAdd(&cursor[d.w], 1);
    col[p0] = s.x;
    col[p1] = s.y;
    col[p2] = s.z;
    col[p3] = s.w;
}
__global__ __launch_bounds__(256) void csr_fill_kernel(const int* __restrict__ src,
                                                       const int* __restrict__ dst,
                                                       int* cursor, int* __restrict__ col,
                                                       int E, int e0) {
    int e = e0 + blockIdx.x * blockDim.x + threadIdx.x;
    if (e >= E) return;
    int s = src[e], d = dst[e];
    int pos = atomicAdd(&cursor[d], 1);
    col[pos] = s;
}

// ---------------- register-tiled GEMM: t[N][128] = (h[N][128] @ W) * dinv[row] ----------------
#define TILE_R 64

__global__ __launch_bounds__(256, 2) void gemm128_tiled(const float* __restrict__ h,
                                                        const float* __restrict__ Wa,
                                                        const float* __restrict__ Wb,
                                                        const float* __restrict__ dinv,
                                                        float* __restrict__ t,
                                                        int N, int ntiles) {
    __shared__ float hl[2][TILE_R * 128];

    const int lane = threadIdx.x & 63;
    const int wav  = threadIdx.x >> 6;
    const int jf4  = threadIdx.x & 31;
    const int rg   = threadIdx.x >> 5;

    const float* wptr;
    int wstride;
    if (Wb) { wptr = (jf4 < 16) ? (Wa + jf4 * 4) : (Wb + (jf4 - 16) * 4); wstride = 64; }
    else    { wptr = Wa + jf4 * 4; wstride = 128; }

    auto stage = [&](int buf, long long tile) {
        if (tile >= ntiles) return;
        long long row0 = tile * TILE_R;
        if (row0 + TILE_R <= N) {
            const float* gbase = h + row0 * 128 + (size_t)wav * (16 * 128) + lane * 4;
            float* lbase = &hl[buf][wav * (16 * 128)];
            #pragma unroll
            for (int m = 0; m < 8; ++m)
                gl_lds16(gbase + m * 256, lbase + m * 256);
        } else {
            for (int i = threadIdx.x; i < TILE_R * 32; i += 256) {
                int rl = i >> 5, k4 = i & 31;
                long long row = row0 + rl;
                float4 v = (row < N) ? ((const float4*)h)[row * 32 + k4]
                                     : make_float4(0.f, 0.f, 0.f, 0.f);
                *(float4*)&hl[buf][rl * 128 + k4 * 4] = v;
            }
        }
    };

    long long tile = blockIdx.x;
    stage(0, tile);
    __syncthreads();
    int cur = 0;

    for (; tile < ntiles; tile += gridDim.x) {
        stage(cur ^ 1, tile + gridDim.x);

        float4 acc[8];
        #pragma unroll
        for (int rr = 0; rr < 8; ++rr) acc[rr] = make_float4(0.f, 0.f, 0.f, 0.f);

        const float* hb = &hl[cur][rg * 8 * 128];
        #pragma unroll 4
        for (int k = 0; k < 128; k += 4) {
            float4 w0 = *(const float4*)&wptr[(size_t)(k + 0) * wstride];
            float4 w1 = *(const float4*)&wptr[(size_t)(k + 1) * wstride];
            float4 w2 = *(const float4*)&wptr[(size_t)(k + 2) * wstride];
            float4 w3 = *(const float4*)&wptr[(size_t)(k + 3) * wstride];
            #pragma unroll
            for (int rr = 0; rr < 8; ++rr) {
                float4 hv = *(const float4*)&hb[rr * 128 + k];
                acc[rr] = f4_fma(w0, hv.x, acc[rr]);
                acc[rr] = f4_fma(w1, hv.y, acc[rr]);
                acc[rr] = f4_fma(w2, hv.z, acc[rr]);
                acc[rr] = f4_fma(w3, hv.w, acc[rr]);
            }
        }

        long long row0 = tile * TILE_R;
        #pragma unroll
        for (int rr = 0; rr < 8; ++rr) {
            long long row = row0 + rg * 8 + rr;
            if (row < N) {
                float di = dinv[row];
                float4 r = acc[rr];
                r.x *= di; r.y *= di; r.z *= di; r.w *= di;
                ((float4*)t)[row * 32 + jf4] = r;
            }
        }
        __syncthreads();
        cur ^= 1;
    }
}

// ---------------- fused agg(layer k) + gemm(layer k+1) ----------------
// Block owns 64 dst rows. Phase A: pull-aggregate + relu into LDS.
// Phase B: register-tiled GEMM from LDS; t_out = (h @ [Wa|Wb]) * dinv[row].
// No block barrier: group grp writes LDS rows grp*8..grp*8+7 and (rg==grp) reads
// exactly those rows -- producer wave == consumer wave.
__global__ __launch_bounds__(256) void fused_agg_gemm(const float4* __restrict__ t4,
                                                      const int* __restrict__ rowptr,
                                                      const int* __restrict__ col,
                                                      const float* __restrict__ dinv,
                                                      const float* __restrict__ bvec,
                                                      const float* __restrict__ Wa,
                                                      const float* __restrict__ Wb,
                                                      float* __restrict__ tout,
                                                      int N) {
    __shared__ float hl[TILE_R * 128];  // 32 KB

    const int grp = threadIdx.x >> 5;   // 0..7
    const int c   = threadIdx.x & 31;   // float4 col
    const long long row0 = (long long)blockIdx.x * TILE_R;

    float4 bb = ((const float4*)bvec)[c];
    #pragma unroll 1
    for (int r = 0; r < 8; ++r) {
        long long v = row0 + grp * 8 + r;
        float4 res;
        if (v < N) {
            int beg = rowptr[v], end = rowptr[v + 1];
            float4 acc0 = t4[(size_t)v * 32 + c];  // self-loop (pre-scaled)
            float4 acc1 = make_float4(0.f, 0.f, 0.f, 0.f);
            float4 acc2 = make_float4(0.f, 0.f, 0.f, 0.f);
            float4 acc3 = make_float4(0.f, 0.f, 0.f, 0.f);
            int e = beg;
            for (; e + 7 < end; e += 8) {
                int s0 = col[e],     s1 = col[e + 1], s2 = col[e + 2], s3 = col[e + 3];
                int s4 = col[e + 4], s5 = col[e + 5], s6 = col[e + 6], s7 = col[e + 7];
                float4 v0 = t4[(size_t)s0 * 32 + c];
                float4 v1 = t4[(size_t)s1 * 32 + c];
                float4 v2 = t4[(size_t)s2 * 32 + c];
                float4 v3 = t4[(size_t)s3 * 32 + c];
                float4 v4 = t4[(size_t)s4 * 32 + c];
                float4 v5 = t4[(size_t)s5 * 32 + c];
                float4 v6 = t4[(size_t)s6 * 32 + c];
                float4 v7 = t4[(size_t)s7 * 32 + c];
                acc0 = f4_add(acc0, v0); acc1 = f4_add(acc1, v1);
                acc2 = f4_add(acc2, v2); acc3 = f4_add(acc3, v3);
                acc0 = f4_add(acc0, v4); acc1 = f4_add(acc1, v5);
                acc2 = f4_add(acc2, v6); acc3 = f4_add(acc3, v7);
            }
            for (; e + 3 < end; e += 4) {
                int s0 = col[e], s1 = col[e + 1], s2 = col[e + 2], s3 = col[e + 3];
                acc0 = f4_add(acc0, t4[(size_t)s0 * 32 + c]);
                acc1 = f4_add(acc1, t4[(size_t)s1 * 32 + c]);
                acc2 = f4_add(acc2, t4[(size_t)s2 * 32 + c]);
                acc3 = f4_add(acc3, t4[(size_t)s3 * 32 + c]);
            }
            for (; e < end; ++e) acc0 = f4_add(acc0, t4[(size_t)col[e] * 32 + c]);
            float di = dinv[v];
            float4 s = f4_add(f4_add(acc0, acc1), f4_add(acc2, acc3));
            res = f4_fma(s, di, bb);
            res.x = fmaxf(res.x, 0.f); res.y = fmaxf(res.y, 0.f);
            res.z = fmaxf(res.z, 0.f); res.w = fmaxf(res.w, 0.f);
        } else {
            res = make_float4(0.f, 0.f, 0.f, 0.f);
        }
        *(float4*)&hl[(grp * 8 + r) * 128 + c * 4] = res;
    }
    // (no __syncthreads: intra-wave LDS RAW only)

    const int jf4 = c;
    const int rg  = grp;
    const float* wptr;
    int wstride;
    if (Wb) { wptr = (jf4 < 16) ? (Wa + jf4 * 4) : (Wb + (jf4 - 16) * 4); wstride = 64; }
    else    { wptr = Wa + jf4 * 4; wstride = 128; }

    float4 acc[8];
    #pragma unroll
    for (int rr = 0; rr < 8; ++rr) acc[rr] = make_float4(0.f, 0.f, 0.f, 0.f);

    const float* hb = &hl[rg * 8 * 128];
    #pragma unroll 4
    for (int k = 0; k < 128; k += 4) {
        float4 w0 = *(const float4*)&wptr[(size_t)(k + 0) * wstride];
        float4 w1 = *(const float4*)&wptr[(size_t)(k + 1) * wstride];
        float4 w2 = *(const float4*)&wptr[(size_t)(k + 2) * wstride];
        float4 w3 = *(const float4*)&wptr[(size_t)(k + 3) * wstride];
        #pragma unroll
        for (int rr = 0; rr < 8; ++rr) {
            float4 hv = *(const float4*)&hb[rr * 128 + k];
            acc[rr] = f4_fma(w0, hv.x, acc[rr]);
            acc[rr] = f4_fma(w1, hv.y, acc[rr]);
            acc[rr] = f4_fma(w2, hv.z, acc[rr]);
            acc[rr] = f4_fma(w3, hv.w, acc[rr]);
        }
    }

    #pragma unroll
    for (int rr = 0; rr < 8; ++rr) {
        long long row = row0 + rg * 8 + rr;
        if (row < N) {
            float di = dinv[row];
            float4 r = acc[rr];
            r.x *= di; r.y *= di; r.z *= di; r.w *= di;
            ((float4*)tout)[row * 32 + jf4] = r;
        }
    }
}

// final layer: cols 0..63 -> mu, 64..127 -> logstd (split output)
__global__ __launch_bounds__(256) void agg_pull_final_kernel(const float4* __restrict__ t4,
                                                             const int* __restrict__ rowptr,
                                                             const int* __restrict__ col,
                                                             const float* __restrict__ dinv,
                                                             const float* __restrict__ bmu,
                                                             const float* __restrict__ bls,
                                                             float4* __restrict__ out4,
                                                             int N) {
    int v = blockIdx.x * 8 + (threadIdx.x >> 5);
    int c = threadIdx.x & 31;
    if (v >= N) return;
    int half = c >> 4, cc = c & 15;
    int beg = rowptr[v], end = rowptr[v + 1];
    float4 acc0 = t4[(size_t)v * 32 + c];
    float4 acc1 = make_float4(0.f, 0.f, 0.f, 0.f);
    float4 acc2 = make_float4(0.f, 0.f, 0.f, 0.f);
    float4 acc3 = make_float4(0.f, 0.f, 0.f, 0.f);
    int e = beg;
    for (; e + 7 < end; e += 8) {
        int s0 = col[e],     s1 = col[e + 1], s2 = col[e + 2], s3 = col[e + 3];
        int s4 = col[e + 4], s5 = col[e + 5], s6 = col[e + 6], s7 = col[e + 7];
        float4 v0 = t4[(size_t)s0 * 32 + c];
        float4 v1 = t4[(size_t)s1 * 32 + c];
        float4 v2 = t4[(size_t)s2 * 32 + c];
        float4 v3 = t4[(size_t)s3 * 32 + c];
        float4 v4 = t4[(size_t)s4 * 32 + c];
        float4 v5 = t4[(size_t)s5 * 32 + c];
        float4 v6 = t4[(size_t)s6 * 32 + c];
        float4 v7 = t4[(size_t)s7 * 32 + c];
        acc0 = f4_add(acc0, v0); acc1 = f4_add(acc1, v1);
        acc2 = f4_add(acc2, v2); acc3 = f4_add(acc3, v3);
        acc0 = f4_add(acc0, v4); acc1 = f4_add(acc1, v5);
        acc2 = f4_add(acc2, v6); acc3 = f4_add(acc3, v7);
    }
    for (; e + 3 < end; e += 4) {
        int s0 = col[e], s1 = col[e + 1], s2 = col[e + 2], s3 = col[e + 3];
        acc0 = f4_add(acc0, t4[(size_t)s0 * 32 + c]);
        acc1 = f4_add(acc1, t4[(size_t)s1 * 32 + c]);
        acc2 = f4_add(acc2, t4[(size_t)s2 * 32 + c]);
        acc3 = f4_add(acc3, t4[(size_t)s3 * 32 + c]);
    }
    for (; e < end; ++e) acc0 = f4_add(acc0, t4[(size_t)col[e] * 32 + c]);
    float di = dinv[v];
    float4 s = f4_add(f4_add(acc0, acc1), f4_add(acc2, acc3));
    float4 bb = half ? ((const float4*)bls)[cc] : ((const float4*)bmu)[cc];
    out4[(size_t)half * N * 16 + (size_t)v * 16 + cc] = f4_fma(s, di, bb);
}

// ---------------- fallback (atomic scatter) kernels ----------------
__global__ __launch_bounds__(256) void deg_init_kernel(float* deg, int N) {
    int i = blockIdx.x * blockDim.x + threadIdx.x;
    if (i < N) deg[i] = 1.0f;
}
__global__ __launch_bounds__(256) void deg_count_kernel(const int* __restrict__ dst, float* deg, int E) {
    int i = blockIdx.x * blockDim.x + threadIdx.x;
    if (i < E) unsafeAtomicAdd(&deg[dst[i]], 1.0f);
}
__global__ __launch_bounds__(256) void deg_rsqrt_kernel(float* deg, int N) {
    int i = blockIdx.x * blockDim.x + threadIdx.x;
    if (i < N) deg[i] = rsqrtf(deg[i]);
}
__global__ __launch_bounds__(256) void gemm128_kernel(const float* __restrict__ h,
                                                      const float* __restrict__ Wa,
                                                      const float* __restrict__ Wb,
                                                      float* __restrict__ t,
                                                      int N, int relu) {
    __shared__ float Wl[128 * 128];
    __shared__ float hl[2][128];
    for (int i = threadIdx.x; i < 128 * 128; i += 256) {
        int k = i >> 7, j = i & 127;
        float w;
        if (Wb) w = (j < 64) ? Wa[k * 64 + j] : Wb[k * 64 + (j - 64)];
        else    w = Wa[i];
        Wl[i] = w;
    }
    __syncthreads();
    int col = threadIdx.x & 127;
    int r   = threadIdx.x >> 7;
    for (long long pair = blockIdx.x; pair * 2 < N; pair += gridDim.x) {
        int row0 = (int)(pair * 2);
        {
            int rr = threadIdx.x >> 7, k = threadIdx.x & 127;
            int row = row0 + rr;
            float v = (row < N) ? h[(size_t)row * 128 + k] : 0.0f;
            if (relu) v = fmaxf(v, 0.0f);
            hl[rr][k] = v;
        }
        __syncthreads();
        float acc = 0.0f;
        #pragma unroll
        for (int k = 0; k < 128; k += 4) {
            float4 hv = *(const float4*)&hl[r][k];
            acc += hv.x * Wl[(k + 0) * 128 + col];
            acc += hv.y * Wl[(k + 1) * 128 + col];
            acc += hv.z * Wl[(k + 2) * 128 + col];
            acc += hv.w * Wl[(k + 3) * 128 + col];
        }
        int row = row0 + r;
        if (row < N) t[(size_t)row * 128 + col] = acc;
        __syncthreads();
    }
}
__global__ __launch_bounds__(256) void init_self_kernel(const float4* __restrict__ t4,
                                                        const float* __restrict__ dinv,
                                                        const float* __restrict__ b,
                                                        float4* __restrict__ out, int N) {
    int idx = blockIdx.x * blockDim.x + threadIdx.x;
    int v = idx >> 5, c = idx & 31;
    if (v >= N) return;
    float di = dinv[v];
    float s = di * di;
    float4 x = t4[(size_t)v * 32 + c];
    float4 bb = ((const float4*)b)[c];
    out[(size_t)v * 32 + c] = make_float4(fmaf(x.x, s, bb.x), fmaf(x.y, s, bb.y),
                                          fmaf(x.z, s, bb.z), fmaf(x.w, s, bb.w));
}
__global__ __launch_bounds__(256) void init_final_kernel(const float4* __restrict__ t4,
                                                         const float* __restrict__ dinv,
                                                         const float* __restrict__ bmu,
                                                         const float* __restrict__ bls,
                                                         float4* __restrict__ out4, int N) {
    int idx = blockIdx.x * blockDim.x + threadIdx.x;
    int v = idx >> 5, c = idx & 31;
    if (v >= N) return;
    int half = c >> 4, cc = c & 15;
    float di = dinv[v];
    float s = di * di;
    float4 x = t4[(size_t)v * 32 + c];
    float4 bb = half ? ((const float4*)bls)[cc] : ((const float4*)bmu)[cc];
    out4[(size_t)half * N * 16 + (size_t)v * 16 + cc] =
        make_float4(fmaf(x.x, s, bb.x), fmaf(x.y, s, bb.y),
                    fmaf(x.z, s, bb.z), fmaf(x.w, s, bb.w));
}
__global__ __launch_bounds__(256) void agg_edge_kernel(const float4* __restrict__ t4,
                                                       const int* __restrict__ src,
                                                       const int* __restrict__ dst,
                                                       const float* __restrict__ dinv,
                                                       float* __restrict__ out, int E) {
    int idx = blockIdx.x * blockDim.x + threadIdx.x;
    int e = idx >> 5, c = idx & 31;
    if (e >= E) return;
    int s = src[e], d = dst[e];
    float w = dinv[s] * dinv[d];
    float4 v = t4[(size_t)s * 32 + c];
    float* o = out + (size_t)d * 128 + c * 4;
    unsafeAtomicAdd(o + 0, v.x * w);
    unsafeAtomicAdd(o + 1, v.y * w);
    unsafeAtomicAdd(o + 2, v.z * w);
    unsafeAtomicAdd(o + 3, v.w * w);
}
__global__ __launch_bounds__(256) void agg_edge_final_kernel(const float4* __restrict__ t4,
                                                             const int* __restrict__ src,
                                                             const int* __restrict__ dst,
                                                             const float* __restrict__ dinv,
                                                             float* __restrict__ out, int N, int E) {
    int idx = blockIdx.x * blockDim.x + threadIdx.x;
    int e = idx >> 5, c = idx & 31;
    if (e >= E) return;
    int s = src[e], d = dst[e];
    int half = c >> 4, cc = c & 15;
    float w = dinv[s] * dinv[d];
    float4 v = t4[(size_t)s * 32 + c];
    float* o = out + (size_t)half * N * 64 + (size_t)d * 64 + cc * 4;
    unsafeAtomicAdd(o + 0, v.x * w);
    unsafeAtomicAdd(o + 1, v.y * w);
    unsafeAtomicAdd(o + 2, v.z * w);
    unsafeAtomicAdd(o + 3, v.w * w);
}

// ---------------- launch ----------------
extern "C" void kernel_launch(void* const* d_in, const int* in_sizes, int n_in,
                              void* d_out, int out_size, void* d_ws, size_t ws_size,
                              hipStream_t stream) {
    const float* x   = (const float*)d_in[0];
    const int*   ei  = (const int*)d_in[1];
    const float* W1  = (const float*)d_in[2];
    const float* b1  = (const float*)d_in[3];
    const float* W2  = (const float*)d_in[4];
    const float* b2  = (const float*)d_in[5];
    const float* Wmu = (const float*)d_in[6];
    const float* bmu = (const float*)d_in[7];
    const float* Wls = (const float*)d_in[8];
    const float* bls = (const float*)d_in[9];

    const int N = in_sizes[0] / 128;
    const int E = in_sizes[1] / 2;
    const int* src = ei;
    const int* dst = ei + E;

    float* out = (float*)d_out;

    auto align256 = [](size_t o) { return (o + 255) & ~(size_t)255; };
    const int B1 = (N + SCAN_CHUNK - 1) / SCAN_CHUNK;

    size_t off = 0;
    size_t o_dinv   = off; off = align256(off + (size_t)N * 4);
    size_t o_t      = off; off = align256(off + (size_t)N * 128 * 4);
    size_t o_t2     = off; off = align256(off + (size_t)N * 128 * 4);
    size_t o_rowptr = off; off = align256(off + (size_t)(N + 1) * 4);
    size_t o_cursor = off; off = align256(off + (size_t)N * 4);       // also cnt
    size_t o_bsum   = off; off = align256(off + (size_t)B1 * 4);
    size_t o_col    = off; off = align256(off + (size_t)E * 4);
    size_t need = off;

    float* dinv = (float*)((char*)d_ws + o_dinv);
    float* t    = (float*)((char*)d_ws + o_t);
    float* t2   = (float*)((char*)d_ws + o_t2);

    const int TB = 256;
    int gN = (N + TB - 1) / TB;
    int gE = (E + TB - 1) / TB;
    int ntiles = (N + TILE_R - 1) / TILE_R;

    if (ws_size >= need) {
        int* rowptr = (int*)((char*)d_ws + o_rowptr);
        int* cursor = (int*)((char*)d_ws + o_cursor);
        int* bsum   = (int*)((char*)d_ws + o_bsum);
        int* col    = (int*)((char*)d_ws + o_col);

        // vectorizable only if E%4==0 (int4 alignment of dst = ei+E); E=1.6M -> yes
        const bool vec4 = ((E & 3) == 0) && ((((uintptr_t)ei) & 15) == 0);
        const int E4 = E >> 2;
        int gE4 = (E4 + TB - 1) / TB;

        // CSR build
        hipMemsetAsync(cursor, 0, (size_t)N * 4, stream);
        if (vec4)
            cnt_count4_kernel<<<gE4, TB, 0, stream>>>((const int4*)dst, cursor, E4);
        else
            cnt_count_kernel<<<gE, TB, 0, stream>>>(dst, cursor, E);
        scan_reduce_kernel<<<B1, TB, 0, stream>>>(cursor, bsum, N);
        scan_bsum_kernel<<<1, 64, 0, stream>>>(bsum, B1, rowptr + N, E);
        scan_write_kernel<<<B1, TB, 0, stream>>>(cursor, bsum, rowptr, cursor, dinv, N);
        if (vec4)
            csr_fill4_kernel<<<gE4, TB, 0, stream>>>((const int4*)src, (const int4*)dst, cursor, col, E4);
        else
            csr_fill_kernel<<<gE, TB, 0, stream>>>(src, dst, cursor, col, E, 0);

        // layer 1: t = (x @ W1) * dinv
        gemm128_tiled<<<512, TB, 0, stream>>>(x, W1, nullptr, dinv, t, N, ntiles);
        // layer 2 fused: h1 = relu(agg(t)+b1); t2 = (h1 @ W2) * dinv
        fused_agg_gemm<<<ntiles, TB, 0, stream>>>((const float4*)t, rowptr, col, dinv, b1, W2, nullptr, t2, N);
        // layer 3 fused: h2 = relu(agg(t2)+b2); t = (h2 @ [Wmu|Wls]) * dinv
        fused_agg_gemm<<<ntiles, TB, 0, stream>>>((const float4*)t2, rowptr, col, dinv, b2, Wmu, Wls, t, N);
        // layer 4: final aggregation -> (mu, logstd)
        agg_pull_final_kernel<<<(N + 7) / 8, TB, 0, stream>>>((const float4*)t, rowptr, col, dinv, bmu, bls, (float4*)out, N);
    } else {
        // fallback: atomic scatter path
        int gN32  = (N * 32 + TB - 1) / TB;
        int gE32h = (int)(((long long)E * 32 + TB - 1) / TB);
        deg_init_kernel<<<gN, TB, 0, stream>>>(dinv, N);
        deg_count_kernel<<<gE, TB, 0, stream>>>(dst, dinv, E);
        deg_rsqrt_kernel<<<gN, TB, 0, stream>>>(dinv, N);

        gemm128_kernel<<<2048, TB, 0, stream>>>(x, W1, nullptr, t, N, 0);
        init_self_kernel<<<gN32, TB, 0, stream>>>((const float4*)t, dinv, b1, (float4*)out, N);
        agg_edge_kernel<<<gE32h, TB, 0, stream>>>((const float4*)t, src, dst, dinv, out, E);

        gemm128_kernel<<<2048, TB, 0, stream>>>(out, W2, nullptr, t, N, 1);
        init_self_kernel<<<gN32, TB, 0, stream>>>((const float4*)t, dinv, b2, (float4*)out, N);
        agg_edge_kernel<<<gE32h, TB, 0, stream>>>((const float4*)t, src, dst, dinv, out, E);

        gemm128_kernel<<<2048, TB, 0, stream>>>(out, Wmu, Wls, t, N, 1);
        init_final_kernel<<<gN32, TB, 0, stream>>>((const float4*)t, dinv, bmu, bls, (float4*)out, N);
        agg_edge_final_kernel<<<gE32h, TB, 0, stream>>>((const float4*)t, src, dst, dinv, out, N, E);
    }
}

// Round 10
// 590.750 us; speedup vs baseline: 1.3992x; 1.2760x over previous
//
#include <hip/hip_runtime.h>
#include <hip/hip_fp16.h>
#include <hip/hip_bf16.h>

// ---------------- small helpers ----------------
__device__ __forceinline__ float4 f4_fma(float4 a, float s, float4 acc) {
    acc.x = fmaf(a.x, s, acc.x); acc.y = fmaf(a.y, s, acc.y);
    acc.z = fmaf(a.z, s, acc.z); acc.w = fmaf(a.w, s, acc.w);
    return acc;
}
__device__ __forceinline__ float4 f4_add(float4 a, float4 b) {
    return make_float4(a.x + b.x, a.y + b.y, a.z + b.z, a.w + b.w);
}

typedef const __attribute__((address_space(1))) unsigned int* gas_u32;
typedef __attribute__((address_space(3))) unsigned int* las_u32;

__device__ __forceinline__ void gl_lds16(const float* g, float* l) {
    __builtin_amdgcn_global_load_lds((gas_u32)(const void*)g, (las_u32)(void*)l, 16, 0, 0);
}

// f32x4 -> f16x4 packed store (8 B)
__device__ __forceinline__ void store_half4(__half* p, float4 v) {
    union { __half2 h[2]; uint2 u; } pk;
    pk.h[0] = __floats2half2_rn(v.x, v.y);
    pk.h[1] = __floats2half2_rn(v.z, v.w);
    *(uint2*)p = pk.u;
}

// accumulate 8 halves (one uint4) into 8 f32 accumulators
__device__ __forceinline__ void acc_half8(float* acc, uint4 raw) {
    union { uint4 u; __half2 h[4]; } pk; pk.u = raw;
    float2 f0 = __half22float2(pk.h[0]);
    float2 f1 = __half22float2(pk.h[1]);
    float2 f2 = __half22float2(pk.h[2]);
    float2 f3 = __half22float2(pk.h[3]);
    acc[0] += f0.x; acc[1] += f0.y; acc[2] += f1.x; acc[3] += f1.y;
    acc[4] += f2.x; acc[5] += f2.y; acc[6] += f3.x; acc[7] += f3.y;
}

// ---------------- degree count ----------------
__global__ __launch_bounds__(256) void cnt_count4_kernel(const int4* __restrict__ dst4, int* cnt, int E4) {
    int i = blockIdx.x * blockDim.x + threadIdx.x;
    if (i < E4) {
        int4 d = dst4[i];
        atomicAdd(&cnt[d.x], 1);
        atomicAdd(&cnt[d.y], 1);
        atomicAdd(&cnt[d.z], 1);
        atomicAdd(&cnt[d.w], 1);
    }
}
__global__ __launch_bounds__(256) void cnt_count_kernel(const int* __restrict__ dst, int* cnt, int E) {
    int i = blockIdx.x * blockDim.x + threadIdx.x;
    if (i < E) atomicAdd(&cnt[dst[i]], 1);
}

// ---------------- exclusive scan (N ~ 100k) ----------------
#define SCAN_CHUNK 4096  // 256 threads * 16

__global__ __launch_bounds__(256) void scan_reduce_kernel(const int* __restrict__ cnt, int* bsum, int N) {
    __shared__ int sdata[256];
    int base = blockIdx.x * SCAN_CHUNK;
    int s = 0;
    for (int k = 0; k < 16; ++k) {
        int i = base + k * 256 + threadIdx.x;
        if (i < N) s += cnt[i];
    }
    sdata[threadIdx.x] = s;
    __syncthreads();
    for (int off = 128; off > 0; off >>= 1) {
        if (threadIdx.x < off) sdata[threadIdx.x] += sdata[threadIdx.x + off];
        __syncthreads();
    }
    if (threadIdx.x == 0) bsum[blockIdx.x] = sdata[0];
}

__global__ void scan_bsum_kernel(int* bsum, int B, int* rowptr_end, int E) {
    if (threadIdx.x == 0 && blockIdx.x == 0) {
        int run = 0;
        for (int i = 0; i < B; ++i) { int v = bsum[i]; bsum[i] = run; run += v; }
        *rowptr_end = E;  // rowptr[N] = E
    }
}

// also emits dinv (rsqrt(deg)) and cursor (= rowptr copy)
__global__ __launch_bounds__(256) void scan_write_kernel(const int* __restrict__ cnt,
                                                         const int* __restrict__ bsum,
                                                         int* rowptr, int* cursor,
                                                         float* dinv, int N) {
    __shared__ int sdata[256];
    int base = blockIdx.x * SCAN_CHUNK;
    int tbase = base + threadIdx.x * 16;
    int loc[16];
    int s = 0;
    for (int k = 0; k < 16; ++k) {
        int i = tbase + k;
        int v = (i < N) ? cnt[i] : 0;
        loc[k] = s; s += v;
    }
    sdata[threadIdx.x] = s;
    __syncthreads();
    for (int off = 1; off < 256; off <<= 1) {
        int v = sdata[threadIdx.x];
        int add = (threadIdx.x >= off) ? sdata[threadIdx.x - off] : 0;
        __syncthreads();
        sdata[threadIdx.x] = v + add;
        __syncthreads();
    }
    int texcl = (threadIdx.x == 0) ? 0 : sdata[threadIdx.x - 1];
    int boff = bsum[blockIdx.x];
    for (int k = 0; k < 16; ++k) {
        int i = tbase + k;
        if (i < N) {
            int rp = boff + texcl + loc[k];
            rowptr[i] = rp;
            cursor[i] = rp;
            dinv[i] = rsqrtf((float)(cnt[i] + 1));
        }
    }
}

// ---------------- csr fill ----------------
__global__ __launch_bounds__(256) void csr_fill4_kernel(const int4* __restrict__ src4,
                                                        const int4* __restrict__ dst4,
                                                        int* cursor, int* __restrict__ col,
                                                        int E4) {
    int i = blockIdx.x * blockDim.x + threadIdx.x;
    if (i >= E4) return;
    int4 s = src4[i];
    int4 d = dst4[i];
    int p0 = atomicAdd(&cursor[d.x], 1);
    int p1 = atomicAdd(&cursor[d.y], 1);
    int p2 = atomicAdd(&cursor[d.z], 1);
    int p3 = atomicAdd(&cursor[d.w], 1);
    col[p0] = s.x;
    col[p1] = s.y;
    col[p2] = s.z;
    col[p3] = s.w;
}
__global__ __launch_bounds__(256) void csr_fill_kernel(const int* __restrict__ src,
                                                       const int* __restrict__ dst,
                                                       int* cursor, int* __restrict__ col,
                                                       int E) {
    int e = blockIdx.x * blockDim.x + threadIdx.x;
    if (e >= E) return;
    int s = src[e], d = dst[e];
    int pos = atomicAdd(&cursor[d], 1);
    col[pos] = s;
}

// ---------------- register-tiled GEMM: t_h[N][128](f16) = (h[N][128](f32) @ W) * dinv[row] ----------------
#define TILE_R 64

__global__ __launch_bounds__(256, 2) void gemm128_tiled(const float* __restrict__ h,
                                                        const float* __restrict__ Wa,
                                                        const float* __restrict__ Wb,
                                                        const float* __restrict__ dinv,
                                                        __half* __restrict__ th,
                                                        int N, int ntiles) {
    __shared__ float hl[2][TILE_R * 128];

    const int lane = threadIdx.x & 63;
    const int wav  = threadIdx.x >> 6;
    const int jf4  = threadIdx.x & 31;
    const int rg   = threadIdx.x >> 5;

    const float* wptr;
    int wstride;
    if (Wb) { wptr = (jf4 < 16) ? (Wa + jf4 * 4) : (Wb + (jf4 - 16) * 4); wstride = 64; }
    else    { wptr = Wa + jf4 * 4; wstride = 128; }

    auto stage = [&](int buf, long long tile) {
        if (tile >= ntiles) return;
        long long row0 = tile * TILE_R;
        if (row0 + TILE_R <= N) {
            const float* gbase = h + row0 * 128 + (size_t)wav * (16 * 128) + lane * 4;
            float* lbase = &hl[buf][wav * (16 * 128)];
            #pragma unroll
            for (int m = 0; m < 8; ++m)
                gl_lds16(gbase + m * 256, lbase + m * 256);
        } else {
            for (int i = threadIdx.x; i < TILE_R * 32; i += 256) {
                int rl = i >> 5, k4 = i & 31;
                long long row = row0 + rl;
                float4 v = (row < N) ? ((const float4*)h)[row * 32 + k4]
                                     : make_float4(0.f, 0.f, 0.f, 0.f);
                *(float4*)&hl[buf][rl * 128 + k4 * 4] = v;
            }
        }
    };

    long long tile = blockIdx.x;
    stage(0, tile);
    __syncthreads();
    int cur = 0;

    for (; tile < ntiles; tile += gridDim.x) {
        stage(cur ^ 1, tile + gridDim.x);

        float4 acc[8];
        #pragma unroll
        for (int rr = 0; rr < 8; ++rr) acc[rr] = make_float4(0.f, 0.f, 0.f, 0.f);

        const float* hb = &hl[cur][rg * 8 * 128];
        #pragma unroll 4
        for (int k = 0; k < 128; k += 4) {
            float4 w0 = *(const float4*)&wptr[(size_t)(k + 0) * wstride];
            float4 w1 = *(const float4*)&wptr[(size_t)(k + 1) * wstride];
            float4 w2 = *(const float4*)&wptr[(size_t)(k + 2) * wstride];
            float4 w3 = *(const float4*)&wptr[(size_t)(k + 3) * wstride];
            #pragma unroll
            for (int rr = 0; rr < 8; ++rr) {
                float4 hv = *(const float4*)&hb[rr * 128 + k];
                acc[rr] = f4_fma(w0, hv.x, acc[rr]);
                acc[rr] = f4_fma(w1, hv.y, acc[rr]);
                acc[rr] = f4_fma(w2, hv.z, acc[rr]);
                acc[rr] = f4_fma(w3, hv.w, acc[rr]);
            }
        }

        long long row0 = tile * TILE_R;
        #pragma unroll
        for (int rr = 0; rr < 8; ++rr) {
            long long row = row0 + rg * 8 + rr;
            if (row < N) {
                float di = dinv[row];
                float4 r = acc[rr];
                r.x *= di; r.y *= di; r.z *= di; r.w *= di;
                store_half4(th + (size_t)row * 128 + jf4 * 4, r);
            }
        }
        __syncthreads();
        cur ^= 1;
    }
}

// ---------------- pull aggregation over f16 t ----------------
// 16 lanes per dst row; lane handles 8 cols (16B). out(f32) = dinv[v]*(sum t_h[col[e]] + t_h[v]) + b
__global__ __launch_bounds__(256) void agg_pull_h_kernel(const __half* __restrict__ th,
                                                         const int* __restrict__ rowptr,
                                                         const int* __restrict__ col,
                                                         const float* __restrict__ dinv,
                                                         const float* __restrict__ b,
                                                         float* __restrict__ out,
                                                         int N, int relu) {
    int v = blockIdx.x * 16 + (threadIdx.x >> 4);
    int c = threadIdx.x & 15;   // 16B chunk (8 halves)
    if (v >= N) return;
    const uint4* tq = (const uint4*)th;  // row stride = 16 uint4
    int beg = rowptr[v], end = rowptr[v + 1];
    float a0[8] = {0,0,0,0,0,0,0,0}, a1[8] = {0,0,0,0,0,0,0,0};
    float a2[8] = {0,0,0,0,0,0,0,0}, a3[8] = {0,0,0,0,0,0,0,0};
    acc_half8(a0, tq[(size_t)v * 16 + c]);  // self-loop (pre-scaled)
    int e = beg;
    for (; e + 3 < end; e += 4) {
        int s0 = col[e], s1 = col[e + 1], s2 = col[e + 2], s3 = col[e + 3];
        uint4 r0 = tq[(size_t)s0 * 16 + c];
        uint4 r1 = tq[(size_t)s1 * 16 + c];
        uint4 r2 = tq[(size_t)s2 * 16 + c];
        uint4 r3 = tq[(size_t)s3 * 16 + c];
        acc_half8(a0, r0); acc_half8(a1, r1); acc_half8(a2, r2); acc_half8(a3, r3);
    }
    for (; e < end; ++e) acc_half8(a0, tq[(size_t)col[e] * 16 + c]);
    float di = dinv[v];
    float4 b0 = *(const float4*)(b + c * 8);
    float4 b1v = *(const float4*)(b + c * 8 + 4);
    float o[8];
    #pragma unroll
    for (int i = 0; i < 8; ++i) {
        float bb = (i < 4) ? (&b0.x)[i] : (&b1v.x)[i - 4];
        float s = (a0[i] + a1[i]) + (a2[i] + a3[i]);
        o[i] = fmaf(s, di, bb);
        if (relu) o[i] = fmaxf(o[i], 0.f);
    }
    float4* op = (float4*)(out + (size_t)v * 128 + c * 8);
    op[0] = make_float4(o[0], o[1], o[2], o[3]);
    op[1] = make_float4(o[4], o[5], o[6], o[7]);
}

// final: lane chunks c<8 -> mu (out[v*64+...]), c>=8 -> logstd (out[N*64 + v*64+...])
__global__ __launch_bounds__(256) void agg_pull_final_h_kernel(const __half* __restrict__ th,
                                                               const int* __restrict__ rowptr,
                                                               const int* __restrict__ col,
                                                               const float* __restrict__ dinv,
                                                               const float* __restrict__ bmu,
                                                               const float* __restrict__ bls,
                                                               float* __restrict__ out,
                                                               int N) {
    int v = blockIdx.x * 16 + (threadIdx.x >> 4);
    int c = threadIdx.x & 15;
    if (v >= N) return;
    const uint4* tq = (const uint4*)th;
    int beg = rowptr[v], end = rowptr[v + 1];
    float a0[8] = {0,0,0,0,0,0,0,0}, a1[8] = {0,0,0,0,0,0,0,0};
    float a2[8] = {0,0,0,0,0,0,0,0}, a3[8] = {0,0,0,0,0,0,0,0};
    acc_half8(a0, tq[(size_t)v * 16 + c]);
    int e = beg;
    for (; e + 3 < end; e += 4) {
        int s0 = col[e], s1 = col[e + 1], s2 = col[e + 2], s3 = col[e + 3];
        uint4 r0 = tq[(size_t)s0 * 16 + c];
        uint4 r1 = tq[(size_t)s1 * 16 + c];
        uint4 r2 = tq[(size_t)s2 * 16 + c];
        uint4 r3 = tq[(size_t)s3 * 16 + c];
        acc_half8(a0, r0); acc_half8(a1, r1); acc_half8(a2, r2); acc_half8(a3, r3);
    }
    for (; e < end; ++e) acc_half8(a0, tq[(size_t)col[e] * 16 + c]);
    float di = dinv[v];
    const float* bp = (c < 8) ? (bmu + c * 8) : (bls + (c - 8) * 8);
    float* obase = (c < 8) ? (out + (size_t)v * 64 + c * 8)
                           : (out + (size_t)N * 64 + (size_t)v * 64 + (size_t)(c - 8) * 8);
    float4 b0 = *(const float4*)bp;
    float4 b1v = *(const float4*)(bp + 4);
    float o[8];
    #pragma unroll
    for (int i = 0; i < 8; ++i) {
        float bb = (i < 4) ? (&b0.x)[i] : (&b1v.x)[i - 4];
        float s = (a0[i] + a1[i]) + (a2[i] + a3[i]);
        o[i] = fmaf(s, di, bb);
    }
    ((float4*)obase)[0] = make_float4(o[0], o[1], o[2], o[3]);
    ((float4*)obase)[1] = make_float4(o[4], o[5], o[6], o[7]);
}

// ---------------- fallback (atomic scatter, f32) kernels ----------------
__global__ __launch_bounds__(256) void deg_init_kernel(float* deg, int N) {
    int i = blockIdx.x * blockDim.x + threadIdx.x;
    if (i < N) deg[i] = 1.0f;
}
__global__ __launch_bounds__(256) void deg_count_kernel(const int* __restrict__ dst, float* deg, int E) {
    int i = blockIdx.x * blockDim.x + threadIdx.x;
    if (i < E) unsafeAtomicAdd(&deg[dst[i]], 1.0f);
}
__global__ __launch_bounds__(256) void deg_rsqrt_kernel(float* deg, int N) {
    int i = blockIdx.x * blockDim.x + threadIdx.x;
    if (i < N) deg[i] = rsqrtf(deg[i]);
}
__global__ __launch_bounds__(256) void gemm128_kernel(const float* __restrict__ h,
                                                      const float* __restrict__ Wa,
                                                      const float* __restrict__ Wb,
                                                      float* __restrict__ t,
                                                      int N, int relu) {
    __shared__ float Wl[128 * 128];
    __shared__ float hl[2][128];
    for (int i = threadIdx.x; i < 128 * 128; i += 256) {
        int k = i >> 7, j = i & 127;
        float w;
        if (Wb) w = (j < 64) ? Wa[k * 64 + j] : Wb[k * 64 + (j - 64)];
        else    w = Wa[i];
        Wl[i] = w;
    }
    __syncthreads();
    int col = threadIdx.x & 127;
    int r   = threadIdx.x >> 7;
    for (long long pair = blockIdx.x; pair * 2 < N; pair += gridDim.x) {
        int row0 = (int)(pair * 2);
        {
            int rr = threadIdx.x >> 7, k = threadIdx.x & 127;
            int row = row0 + rr;
            float v = (row < N) ? h[(size_t)row * 128 + k] : 0.0f;
            if (relu) v = fmaxf(v, 0.0f);
            hl[rr][k] = v;
        }
        __syncthreads();
        float acc = 0.0f;
        #pragma unroll
        for (int k = 0; k < 128; k += 4) {
            float4 hv = *(const float4*)&hl[r][k];
            acc += hv.x * Wl[(k + 0) * 128 + col];
            acc += hv.y * Wl[(k + 1) * 128 + col];
            acc += hv.z * Wl[(k + 2) * 128 + col];
            acc += hv.w * Wl[(k + 3) * 128 + col];
        }
        int row = row0 + r;
        if (row < N) t[(size_t)row * 128 + col] = acc;
        __syncthreads();
    }
}
__global__ __launch_bounds__(256) void init_self_kernel(const float4* __restrict__ t4,
                                                        const float* __restrict__ dinv,
                                                        const float* __restrict__ b,
                                                        float4* __restrict__ out, int N) {
    int idx = blockIdx.x * blockDim.x + threadIdx.x;
    int v = idx >> 5, c = idx & 31;
    if (v >= N) return;
    float di = dinv[v];
    float s = di * di;
    float4 x = t4[(size_t)v * 32 + c];
    float4 bb = ((const float4*)b)[c];
    out[(size_t)v * 32 + c] = make_float4(fmaf(x.x, s, bb.x), fmaf(x.y, s, bb.y),
                                          fmaf(x.z, s, bb.z), fmaf(x.w, s, bb.w));
}
__global__ __launch_bounds__(256) void init_final_kernel(const float4* __restrict__ t4,
                                                         const float* __restrict__ dinv,
                                                         const float* __restrict__ bmu,
                                                         const float* __restrict__ bls,
                                                         float4* __restrict__ out4, int N) {
    int idx = blockIdx.x * blockDim.x + threadIdx.x;
    int v = idx >> 5, c = idx & 31;
    if (v >= N) return;
    int half = c >> 4, cc = c & 15;
    float di = dinv[v];
    float s = di * di;
    float4 x = t4[(size_t)v * 32 + c];
    float4 bb = half ? ((const float4*)bls)[cc] : ((const float4*)bmu)[cc];
    out4[(size_t)half * N * 16 + (size_t)v * 16 + cc] =
        make_float4(fmaf(x.x, s, bb.x), fmaf(x.y, s, bb.y),
                    fmaf(x.z, s, bb.z), fmaf(x.w, s, bb.w));
}
__global__ __launch_bounds__(256) void agg_edge_kernel(const float4* __restrict__ t4,
                                                       const int* __restrict__ src,
                                                       const int* __restrict__ dst,
                                                       const float* __restrict__ dinv,
                                                       float* __restrict__ out, int E) {
    int idx = blockIdx.x * blockDim.x + threadIdx.x;
    int e = idx >> 5, c = idx & 31;
    if (e >= E) return;
    int s = src[e], d = dst[e];
    float w = dinv[s] * dinv[d];
    float4 v = t4[(size_t)s * 32 + c];
    float* o = out + (size_t)d * 128 + c * 4;
    unsafeAtomicAdd(o + 0, v.x * w);
    unsafeAtomicAdd(o + 1, v.y * w);
    unsafeAtomicAdd(o + 2, v.z * w);
    unsafeAtomicAdd(o + 3, v.w * w);
}
__global__ __launch_bounds__(256) void agg_edge_final_kernel(const float4* __restrict__ t4,
                                                             const int* __restrict__ src,
                                                             const int* __restrict__ dst,
                                                             const float* __restrict__ dinv,
                                                             float* __restrict__ out, int N, int E) {
    int idx = blockIdx.x * blockDim.x + threadIdx.x;
    int e = idx >> 5, c = idx & 31;
    if (e >= E) return;
    int s = src[e], d = dst[e];
    int half = c >> 4, cc = c & 15;
    float w = dinv[s] * dinv[d];
    float4 v = t4[(size_t)s * 32 + c];
    float* o = out + (size_t)half * N * 64 + (size_t)d * 64 + cc * 4;
    unsafeAtomicAdd(o + 0, v.x * w);
    unsafeAtomicAdd(o + 1, v.y * w);
    unsafeAtomicAdd(o + 2, v.z * w);
    unsafeAtomicAdd(o + 3, v.w * w);
}

// ---------------- launch ----------------
extern "C" void kernel_launch(void* const* d_in, const int* in_sizes, int n_in,
                              void* d_out, int out_size, void* d_ws, size_t ws_size,
                              hipStream_t stream) {
    const float* x   = (const float*)d_in[0];
    const int*   ei  = (const int*)d_in[1];
    const float* W1  = (const float*)d_in[2];
    const float* b1  = (const float*)d_in[3];
    const float* W2  = (const float*)d_in[4];
    const float* b2  = (const float*)d_in[5];
    const float* Wmu = (const float*)d_in[6];
    const float* bmu = (const float*)d_in[7];
    const float* Wls = (const float*)d_in[8];
    const float* bls = (const float*)d_in[9];

    const int N = in_sizes[0] / 128;
    const int E = in_sizes[1] / 2;
    const int* src = ei;
    const int* dst = ei + E;

    float* out = (float*)d_out;  // f32 h buffer for hidden layers, final mu|ls

    auto align256 = [](size_t o) { return (o + 255) & ~(size_t)255; };
    const int B1 = (N + SCAN_CHUNK - 1) / SCAN_CHUNK;

    size_t off = 0;
    size_t o_dinv   = off; off = align256(off + (size_t)N * 4);
    size_t o_t      = off; off = align256(off + (size_t)N * 128 * 4);  // sized f32 for fallback; f16 path uses half
    size_t o_rowptr = off; off = align256(off + (size_t)(N + 1) * 4);
    size_t o_cursor = off; off = align256(off + (size_t)N * 4);        // also cnt
    size_t o_bsum   = off; off = align256(off + (size_t)B1 * 4);
    size_t o_col    = off; off = align256(off + (size_t)E * 4);
    size_t need = off;

    float*  dinv = (float*)((char*)d_ws + o_dinv);
    float*  tf   = (float*)((char*)d_ws + o_t);   // fallback f32 t
    __half* th   = (__half*)((char*)d_ws + o_t);  // main-path f16 t (reused for all 3 layers)

    const int TB = 256;
    int gN = (N + TB - 1) / TB;
    int gE = (E + TB - 1) / TB;
    int ntiles = (N + TILE_R - 1) / TILE_R;

    if (ws_size >= need) {
        int* rowptr = (int*)((char*)d_ws + o_rowptr);
        int* cursor = (int*)((char*)d_ws + o_cursor);
        int* bsum   = (int*)((char*)d_ws + o_bsum);
        int* col    = (int*)((char*)d_ws + o_col);

        const bool vec4 = ((E & 3) == 0) && ((((uintptr_t)ei) & 15) == 0);
        const int E4 = E >> 2;
        int gE4 = (E4 + TB - 1) / TB;

        // CSR build
        hipMemsetAsync(cursor, 0, (size_t)N * 4, stream);
        if (vec4)
            cnt_count4_kernel<<<gE4, TB, 0, stream>>>((const int4*)dst, cursor, E4);
        else
            cnt_count_kernel<<<gE, TB, 0, stream>>>(dst, cursor, E);
        scan_reduce_kernel<<<B1, TB, 0, stream>>>(cursor, bsum, N);
        scan_bsum_kernel<<<1, 64, 0, stream>>>(bsum, B1, rowptr + N, E);
        scan_write_kernel<<<B1, TB, 0, stream>>>(cursor, bsum, rowptr, cursor, dinv, N);
        if (vec4)
            csr_fill4_kernel<<<gE4, TB, 0, stream>>>((const int4*)src, (const int4*)dst, cursor, col, E4);
        else
            csr_fill_kernel<<<gE, TB, 0, stream>>>(src, dst, cursor, col, E);

        int gPull = (N + 15) / 16;
        // layer 1: t = f16((x @ W1) * dinv)
        gemm128_tiled<<<512, TB, 0, stream>>>(x, W1, nullptr, dinv, th, N, ntiles);
        // h1(out,f32) = relu(agg(t)+b1)
        agg_pull_h_kernel<<<gPull, TB, 0, stream>>>(th, rowptr, col, dinv, b1, out, N, 1);
        // layer 2
        gemm128_tiled<<<512, TB, 0, stream>>>(out, W2, nullptr, dinv, th, N, ntiles);
        agg_pull_h_kernel<<<gPull, TB, 0, stream>>>(th, rowptr, col, dinv, b2, out, N, 1);
        // layer 3+4 fused columns [Wmu|Wls]
        gemm128_tiled<<<512, TB, 0, stream>>>(out, Wmu, Wls, dinv, th, N, ntiles);
        agg_pull_final_h_kernel<<<gPull, TB, 0, stream>>>(th, rowptr, col, dinv, bmu, bls, out, N);
    } else {
        // fallback: atomic scatter path (f32)
        int gN32  = (N * 32 + TB - 1) / TB;
        int gE32h = (int)(((long long)E * 32 + TB - 1) / TB);
        deg_init_kernel<<<gN, TB, 0, stream>>>(dinv, N);
        deg_count_kernel<<<gE, TB, 0, stream>>>(dst, dinv, E);
        deg_rsqrt_kernel<<<gN, TB, 0, stream>>>(dinv, N);

        gemm128_kernel<<<2048, TB, 0, stream>>>(x, W1, nullptr, tf, N, 0);
        init_self_kernel<<<gN32, TB, 0, stream>>>((const float4*)tf, dinv, b1, (float4*)out, N);
        agg_edge_kernel<<<gE32h, TB, 0, stream>>>((const float4*)tf, src, dst, dinv, out, E);

        gemm128_kernel<<<2048, TB, 0, stream>>>(out, W2, nullptr, tf, N, 1);
        init_self_kernel<<<gN32, TB, 0, stream>>>((const float4*)tf, dinv, b2, (float4*)out, N);
        agg_edge_kernel<<<gE32h, TB, 0, stream>>>((const float4*)tf, src, dst, dinv, out, E);

        gemm128_kernel<<<2048, TB, 0, stream>>>(out, Wmu, Wls, tf, N, 1);
        init_final_kernel<<<gN32, TB, 0, stream>>>((const float4*)tf, dinv, bmu, bls, (float4*)out, N);
        agg_edge_final_kernel<<<gE32h, TB, 0, stream>>>((const float4*)tf, src, dst, dinv, out, N, E);
    }
}